// Round 4
// baseline (310.277 us; speedup 1.0000x reference)
//
#include <hip/hip_runtime.h>

// Problem constants (match reference)
#define BATCH   8
#define LEN     2048
#define DMODEL  512
#define T_MAX   200.0f

// clang-native 4-float vector for __builtin_nontemporal_store.
typedef float floatx4 __attribute__((ext_vector_type(4)));

// Fill-shaped streaming kernel.
// The whole output (scores | emb | tdiff, 302 MB) is treated as ONE flat
// float4 array. 2048 blocks x 256 threads = exactly 8 blocks/CU on 256 CUs:
// one full residency, zero block churn. Each block owns one contiguous
// 144 KB region (36 strides x 256 chunks x 16 B) and streams it in order --
// the same store shape as __amd_rocclr_fillBufferAligned, which sustains
// 6.3 TB/s on this very buffer. Per chunk we derive (array,row,col) from the
// flat index with shifts/masks (all extents are powers of 2) and compute the
// SAME bit-identical math as the verified 295us kernel.
//
// Region layout in float4 units:
//   scores [0, 8388608)           8*2048*2048/4
//   emb    [8388608, 10485760)    8*2048*512/4
//   tdiff  [10485760, 18874368)
// Waves never straddle a scores-row (512 chunks/row, 64 chunks/wave) so the
// row index i and the uniform t[row] load are wave-uniform; the array-select
// branch is wave-uniform except in the 2 boundary blocks.

#define SC_CHUNKS   8388608u
#define EMB_CHUNKS  2097152u
#define TD_CHUNKS   8388608u
#define EMB_BASE    SC_CHUNKS
#define TD_BASE     (SC_CHUNKS + EMB_CHUNKS)
#define NBLOCKS     2048
#define ITERS       36              // (SC+EMB+TD) / (NBLOCKS*256) == 36 exactly

__global__ __launch_bounds__(256) void fused_stream_kernel(
    const float* __restrict__ t,        // [B*L]
    const float* __restrict__ ls_p,     // [1]
    const float* __restrict__ gate_p,   // [2]
    float* __restrict__ out)            // flat scores|emb|tdiff
{
    const unsigned tid  = threadIdx.x;
    const unsigned base = blockIdx.x * (ITERS * 256u);

    // learned params (wave-uniform)
    const float ls      = log1pf(__expf(ls_p[0]));            // softplus
    const float inv_ls2 = 1.0f / (ls * ls);
    const float l = 1.0f / (1.0f + __expf(-gate_p[0]));       // sigmoid
    const float s = 1.0f / (1.0f + __expf(-gate_p[1]));
    const float inv_s2 = 2.0f / s;                            // for 2*u
    const float invT   = 1.0f / T_MAX;
    const float c = -9.210340371976184f * (2.0f / (float)DMODEL); // -ln(1e4)*2/D

    floatx4* outv = (floatx4*)out;

#pragma unroll 4
    for (int it = 0; it < ITERS; ++it) {
        const unsigned g = base + (unsigned)it * 256u + tid;  // float4 chunk id

        if (g < EMB_BASE) {
            // ---- scores chunk ----
            const unsigned e   = g << 2;                 // float index
            const unsigned b   = e >> 22;                // / (L*L)
            const unsigned rem = e & ((1u << 22) - 1);
            const unsigned i   = rem >> 11;              // row in [0,L)
            const unsigned j   = rem & (LEN - 1);        // first of 4 cols
            const float ti = t[(b << 11) + i];           // wave-uniform
            const float4 tj = *(const float4*)(t + (b << 11) + j);
            const float tjk[4] = {tj.x, tj.y, tj.z, tj.w};
            floatx4 o;
#pragma unroll
            for (int k = 0; k < 4; ++k) {
                float d  = ti - tjk[k];
                float ad = fabsf(d);
                float kern = __expf(-ad * ad * inv_ls2);
                float u2 = (ad * invT - l) * inv_s2;     // 2*(d/T-l)/s
                // 1 + tanh(u) == 2 * sigmoid(2u)
                float gate = __fdividef(2.0f, 1.0f + __expf(-u2));
                o[k] = (j + (unsigned)k <= i) ? kern * gate : 0.0f;
            }
            __builtin_nontemporal_store(o, outv + g);
        } else if (g < TD_BASE) {
            // ---- embedding chunk ----
            const unsigned e   = (g - EMB_BASE) << 2;    // float index in emb
            const unsigned row = e >> 9;                 // / DMODEL
            const unsigned d0  = e & (DMODEL - 1);
            const float tv = t[row];                     // wave-uniform
            floatx4 o;
            o.x = __sinf(tv * __expf(c * (float)(d0 + 0)));  // even -> sin
            o.y = __cosf(tv * __expf(c * (float)(d0 + 1)));  // odd  -> cos
            o.z = __sinf(tv * __expf(c * (float)(d0 + 2)));
            o.w = __cosf(tv * __expf(c * (float)(d0 + 3)));
            __builtin_nontemporal_store(o, outv + g);
        } else {
            // ---- tdiff chunk ----
            const unsigned e   = (g - TD_BASE) << 2;
            const unsigned b   = e >> 22;
            const unsigned rem = e & ((1u << 22) - 1);
            const unsigned i   = rem >> 11;
            const unsigned j   = rem & (LEN - 1);
            const float ti = t[(b << 11) + i];           // wave-uniform
            const float4 tj = *(const float4*)(t + (b << 11) + j);
            floatx4 o;
            o.x = ti - tj.x;
            o.y = ti - tj.y;
            o.z = ti - tj.z;
            o.w = ti - tj.w;
            __builtin_nontemporal_store(o, outv + g);
        }
    }
}

extern "C" void kernel_launch(void* const* d_in, const int* in_sizes, int n_in,
                              void* d_out, int out_size, void* d_ws, size_t ws_size,
                              hipStream_t stream) {
    // inputs: [0]=event_type (int, unused), [1]=event_time (f32, B*L),
    //         [2]=length_scale_param (f32,1), [3]=gate_params (f32,2)
    const float* t      = (const float*)d_in[1];
    const float* ls_p   = (const float*)d_in[2];
    const float* gate_p = (const float*)d_in[3];

    fused_stream_kernel<<<NBLOCKS, 256, 0, stream>>>(
        t, ls_p, gate_p, (float*)d_out);
}